// Round 6
// baseline (432.628 us; speedup 1.0000x reference)
//
#include <hip/hip_runtime.h>
#include <math.h>

#define B 128
#define N 512
#define M 512
#define D 128

typedef __attribute__((ext_vector_type(8))) short s16x8;
typedef __attribute__((ext_vector_type(4))) short s16x4;
typedef __attribute__((ext_vector_type(4))) float f32x4;
typedef __attribute__((ext_vector_type(16))) float f32x16;

#define MFMA16(a, b, c) __builtin_amdgcn_mfma_f32_16x16x32_bf16(a, b, c, 0, 0, 0)
#define MFMA32(a, b, c) __builtin_amdgcn_mfma_f32_32x32x16_bf16(a, b, c, 0, 0, 0)

__device__ __forceinline__ void gload16(const void* g, void* l) {
    __builtin_amdgcn_global_load_lds(
        (const __attribute__((address_space(1))) unsigned int*)g,
        (__attribute__((address_space(3))) unsigned int*)l, 16, 0, 0);
}

__device__ __forceinline__ float fast_tanh(float x) {
    x = fminf(fmaxf(x, -15.f), 15.f);
    float E = __expf(2.f * x);
    return 1.f - 2.f / (E + 1.f);
}

// Truncation split: x ~= hi + lo
__device__ __forceinline__ void fsplit(float x, short& h, short& l) {
    unsigned u = __float_as_uint(x);
    h = (short)(u >> 16);
    float fh = __uint_as_float(u & 0xffff0000u);
    l = (short)(__float_as_uint(x - fh) >> 16);
}

__device__ __forceinline__ void fsplit8(float4 x0, float4 x1, s16x8& h, s16x8& l) {
    short a, b;
    fsplit(x0.x, a, b); h[0] = a; l[0] = b;
    fsplit(x0.y, a, b); h[1] = a; l[1] = b;
    fsplit(x0.z, a, b); h[2] = a; l[2] = b;
    fsplit(x0.w, a, b); h[3] = a; l[3] = b;
    fsplit(x1.x, a, b); h[4] = a; l[4] = b;
    fsplit(x1.y, a, b); h[5] = a; l[5] = b;
    fsplit(x1.z, a, b); h[6] = a; l[6] = b;
    fsplit(x1.w, a, b); h[7] = a; l[7] = b;
}

// EB = exp(-a1ls*cd + ninf) for 8 elements, split to bf16 hi/lo
__device__ __forceinline__ void ebsplit(float4 c0, float4 c1, float4 f0, float4 f1,
                                        float a1ls, s16x8& ah, s16x8& al) {
    float4 e0, e1;
    e0.x = __expf(fmaf(-a1ls, c0.x, f0.x));
    e0.y = __expf(fmaf(-a1ls, c0.y, f0.y));
    e0.z = __expf(fmaf(-a1ls, c0.z, f0.z));
    e0.w = __expf(fmaf(-a1ls, c0.w, f0.w));
    e1.x = __expf(fmaf(-a1ls, c1.x, f1.x));
    e1.y = __expf(fmaf(-a1ls, c1.y, f1.y));
    e1.z = __expf(fmaf(-a1ls, c1.z, f1.z));
    e1.w = __expf(fmaf(-a1ls, c1.w, f1.w));
    fsplit8(e0, e1, ah, al);
}

__global__ void k_prep_w(const float* __restrict__ Wk, const float* __restrict__ Wv,
                         const float* __restrict__ Wq,
                         unsigned short* __restrict__ Wk_hi, unsigned short* __restrict__ Wk_lo,
                         unsigned short* __restrict__ Wv_hi, unsigned short* __restrict__ Wv_lo,
                         unsigned short* __restrict__ Wq_hi, unsigned short* __restrict__ Wq_lo) {
    int i = blockIdx.x * 256 + threadIdx.x;  // 0..49151
    short h, l;
    if (i < 16384) {
        fsplit(Wk[i], h, l); Wk_hi[i] = (unsigned short)h; Wk_lo[i] = (unsigned short)l;
    } else if (i < 32768) {
        int j = i - 16384;
        fsplit(Wv[j], h, l); Wv_hi[j] = (unsigned short)h; Wv_lo[j] = (unsigned short)l;
    } else {
        int j = i - 32768; int e = j >> 7, d = j & 127;
        fsplit(Wq[e * 129 + d], h, l); Wq_hi[j] = (unsigned short)h; Wq_lo[j] = (unsigned short)l;
    }
}

// k = enc@Wk^T, v = enc@Wv^T; store EK^T/(EK*V)^T bf16 hi/lo [b][e][m],
// SWIZZLED for the 32x32x16 consumer: within each 16-m group, 8-m chunk c
// stored at physical position c ^ (e&1).
__global__ __launch_bounds__(256) void k_kv(const float* __restrict__ enc,
        const unsigned short* __restrict__ Wk_hi, const unsigned short* __restrict__ Wk_lo,
        const unsigned short* __restrict__ Wv_hi, const unsigned short* __restrict__ Wv_lo,
        unsigned short* __restrict__ EKT_hi, unsigned short* __restrict__ EKT_lo,
        unsigned short* __restrict__ EKVT_hi, unsigned short* __restrict__ EKVT_lo) {
    int b = blockIdx.y;
    int wave = threadIdx.x >> 6, lane = threadIdx.x & 63;
    int row = lane & 15, kg = lane >> 4;
    int m0 = blockIdx.x * 64 + wave * 16;
    f32x4 acc[16];
#pragma unroll
    for (int i = 0; i < 16; i++) acc[i] = (f32x4)0.f;
    const float* ap = enc + ((size_t)b * M + m0 + row) * D + kg * 8;
#pragma unroll
    for (int ks = 0; ks < 4; ks++) {
        float4 x0 = *(const float4*)(ap + ks * 32);
        float4 x1 = *(const float4*)(ap + ks * 32 + 4);
        s16x8 ah, al;
        fsplit8(x0, x1, ah, al);
        int wb = ks * 32 + kg * 8;
#pragma unroll
        for (int ct = 0; ct < 8; ct++) {
            int e = ct * 16 + row;
            s16x8 bh = *(const s16x8*)(Wk_hi + e * D + wb);
            s16x8 bl = *(const s16x8*)(Wk_lo + e * D + wb);
            acc[ct] = MFMA16(ah, bh, acc[ct]);
            acc[ct] = MFMA16(al, bh, acc[ct]);
            acc[ct] = MFMA16(ah, bl, acc[ct]);
            bh = *(const s16x8*)(Wv_hi + e * D + wb);
            bl = *(const s16x8*)(Wv_lo + e * D + wb);
            acc[8 + ct] = MFMA16(ah, bh, acc[8 + ct]);
            acc[8 + ct] = MFMA16(al, bh, acc[8 + ct]);
            acc[8 + ct] = MFMA16(ah, bl, acc[8 + ct]);
        }
    }
#pragma unroll
    for (int ct = 0; ct < 8; ct++) {
        int e = ct * 16 + row;
        s16x4 ekh, ekl, evh, evl;
#pragma unroll
        for (int r = 0; r < 4; r++) {
            float ek = __expf(acc[ct][r]);
            float ev = ek * acc[8 + ct][r];
            short h, l;
            fsplit(ek, h, l); ekh[r] = h; ekl[r] = l;
            fsplit(ev, h, l); evh[r] = h; evl[r] = l;
        }
        // logical m = m0 + kg*4; 16-m group chunk c = kg>>1, in-chunk off = (kg&1)*4
        int p = (kg >> 1) ^ (e & 1);
        size_t o = ((size_t)b * D + e) * M + m0 + p * 8 + (kg & 1) * 4;
        *(s16x4*)(EKT_hi + o) = ekh;
        *(s16x4*)(EKT_lo + o) = ekl;
        *(s16x4*)(EKVT_hi + o) = evh;
        *(s16x4*)(EKVT_lo + o) = evl;
    }
}

// q = [encl, load]@Wq^T; SQ = sigmoid(q) f32 [b][n][e]
__global__ __launch_bounds__(256) void k_q(const float* __restrict__ encl,
        const float* __restrict__ loadv, const float* __restrict__ Wq,
        const unsigned short* __restrict__ Wq_hi, const unsigned short* __restrict__ Wq_lo,
        float* __restrict__ SQ) {
    int b = blockIdx.y;
    int wave = threadIdx.x >> 6, lane = threadIdx.x & 63;
    int row = lane & 15, kg = lane >> 4;
    int n0 = blockIdx.x * 64 + wave * 16;
    f32x4 acc[8];
#pragma unroll
    for (int i = 0; i < 8; i++) acc[i] = (f32x4)0.f;
    const float* ap = encl + ((size_t)b * N + n0 + row) * D + kg * 8;
#pragma unroll
    for (int ks = 0; ks < 4; ks++) {
        float4 x0 = *(const float4*)(ap + ks * 32);
        float4 x1 = *(const float4*)(ap + ks * 32 + 4);
        s16x8 ah, al;
        fsplit8(x0, x1, ah, al);
        int wb = ks * 32 + kg * 8;
#pragma unroll
        for (int ct = 0; ct < 8; ct++) {
            int e = ct * 16 + row;
            s16x8 bh = *(const s16x8*)(Wq_hi + e * D + wb);
            s16x8 bl = *(const s16x8*)(Wq_lo + e * D + wb);
            acc[ct] = MFMA16(ah, bh, acc[ct]);
            acc[ct] = MFMA16(al, bh, acc[ct]);
            acc[ct] = MFMA16(ah, bl, acc[ct]);
        }
    }
#pragma unroll
    for (int r = 0; r < 4; r++) {
        int n = n0 + kg * 4 + r;
        float lv = loadv[(size_t)b * N + n];
        size_t ro = ((size_t)b * N + n) * D;
#pragma unroll
        for (int ct = 0; ct < 8; ct++) {
            int e = ct * 16 + row;
            float q = acc[ct][r] + lv * Wq[e * 129 + 128];
            SQ[ro + e] = 1.f / (1.f + __expf(-q));
        }
    }
}

// num=EB@EKV, den=EB@EK via 32x32x16 MFMA. Wave = 32 n x 64 e; block = 4 waves
// (2 ng x 2 eh) = 64 n x 128 e. BK=16 phases (32), 16 KB/buf dbuf -> 32 KB LDS,
// 3 blocks/CU. Grid 1024 XCD-bijective.
__global__ __launch_bounds__(256, 3) void k_numden(
        const float* __restrict__ cd, const float* __restrict__ ninf,
        const unsigned short* __restrict__ EKVT_hi, const unsigned short* __restrict__ EKVT_lo,
        const unsigned short* __restrict__ EKT_hi, const unsigned short* __restrict__ EKT_lo,
        float* __restrict__ SQ,
        const float* __restrict__ a1p, const float* __restrict__ lsp) {
    int o = blockIdx.x;
    int xcd = o & 7, j = o >> 3;       // j 0..127
    int b = ((j >> 3) << 3) + xcd;     // 16 b's per XCD
    int nb = j & 7;
    int w = threadIdx.x >> 6, lane = threadIdx.x & 63;
    int ng = w >> 1, eh = w & 1;
    int col = lane & 31, kh = lane >> 5;   // col: e for B/D, n-row for A
    int n0 = nb * 64 + ng * 32;
    __shared__ __align__(16) char lds[2][16384];  // [4 arr][128 e][16 m x 2B], swizzled
    float a1ls = a1p[0] * lsp[0];
    const char* gbase = (const char*)(w == 0 ? EKVT_hi : w == 1 ? EKVT_lo
                                    : w == 2 ? EKT_hi : EKT_lo)
                        + (size_t)b * D * M * 2;
    f32x16 accN0 = (f32x16)0.f, accN1 = (f32x16)0.f;
    f32x16 accD0 = (f32x16)0.f, accD1 = (f32x16)0.f;
    const float* cdp = cd + ((size_t)b * N + n0 + col) * M + kh * 8;
    const float* nfp = ninf + ((size_t)b * N + n0 + col) * M + kh * 8;
    // B-read base: e = eh*64 + et*32 + col; swz half = kh ^ (e&1); conflict-free quads
    int rb = eh * 2048 + col * 32 + ((kh ^ (lane & 1)) << 4);

#define STAGE_ND(buf, mt)                                                      \
    _Pragma("unroll")                                                          \
    for (int jv = 0; jv < 4; jv++) {                                           \
        int flat = jv * 64 + lane;                                             \
        gload16(gbase + (size_t)(flat >> 1) * 1024 + (mt) * 32 + (flat & 1) * 16, \
                lds[buf] + w * 4096 + flat * 16);                              \
    }

    // prologue
    float4 c0 = *(const float4*)(cdp), c1 = *(const float4*)(cdp + 4);
    float4 f0 = *(const float4*)(nfp), f1 = *(const float4*)(nfp + 4);
    STAGE_ND(0, 0)

#pragma unroll 2
    for (int mt = 0; mt < 32; mt++) {
        int cur = mt & 1;
        __syncthreads();   // drains stages of buf[cur] (issued a full phase ago)
        s16x8 ah, al;
        ebsplit(c0, c1, f0, f1, a1ls, ah, al);
        if (mt < 31) {
            int m = (mt + 1) * 16;
            c0 = *(const float4*)(cdp + m); c1 = *(const float4*)(cdp + m + 4);
            f0 = *(const float4*)(nfp + m); f1 = *(const float4*)(nfp + m + 4);
            STAGE_ND(cur ^ 1, mt + 1)
        }
        const char* L = lds[cur];
        {
            int roff = rb;                                   // et = 0
            s16x8 vh = *(const s16x8*)(L + roff);            // EKVT_hi
            s16x8 vl = *(const s16x8*)(L + 4096 + roff);     // EKVT_lo
            s16x8 th = *(const s16x8*)(L + 8192 + roff);     // EKT_hi
            s16x8 tl = *(const s16x8*)(L + 12288 + roff);    // EKT_lo
            accN0 = MFMA32(ah, vh, accN0);
            accN0 = MFMA32(al, vh, accN0);
            accN0 = MFMA32(ah, vl, accN0);
            accD0 = MFMA32(ah, th, accD0);
            accD0 = MFMA32(al, th, accD0);
            accD0 = MFMA32(ah, tl, accD0);
        }
        {
            int roff = 1024 + rb;                            // et = 1
            s16x8 vh = *(const s16x8*)(L + roff);
            s16x8 vl = *(const s16x8*)(L + 4096 + roff);
            s16x8 th = *(const s16x8*)(L + 8192 + roff);
            s16x8 tl = *(const s16x8*)(L + 12288 + roff);
            accN1 = MFMA32(ah, vh, accN1);
            accN1 = MFMA32(al, vh, accN1);
            accN1 = MFMA32(ah, vl, accN1);
            accD1 = MFMA32(ah, th, accD1);
            accD1 = MFMA32(al, th, accD1);
            accD1 = MFMA32(ah, tl, accD1);
        }
    }
    // writeback: D row = (r&3)+8*(r>>2)+4*kh, col = e
    size_t rowbase = ((size_t)b * N + n0 + 4 * kh) * D + eh * 64 + col;
#pragma unroll
    for (int et = 0; et < 2; et++) {
        f32x16 aN = et ? accN1 : accN0;
        f32x16 aD = et ? accD1 : accD0;
#pragma unroll
        for (int r = 0; r < 16; r++) {
            int dn = (r & 3) + 8 * (r >> 2);
            size_t idx = rowbase + (size_t)dn * D + et * 32;
            float num = aN[r], den = aD[r];
            float ww = (den != 0.f) ? num / den : 0.f;
            float aafm = SQ[idx] * ww;
            unsigned u = __float_as_uint(aafm);
            unsigned hi = u >> 16;
            float fh = __uint_as_float(u & 0xffff0000u);
            unsigned lo = __float_as_uint(aafm - fh) >> 16;
            SQ[idx] = __uint_as_float(hi | (lo << 16));
        }
    }
}

// Split enc -> bf16 hi/lo [b][m][128e], SWIZZLED: 8-e chunk c at c ^ (m&7)
__global__ void k_encsplit(const float* __restrict__ enc,
                           unsigned short* __restrict__ Eh, unsigned short* __restrict__ El) {
    size_t i = (size_t)blockIdx.x * 256 + threadIdx.x;   // chunk id
    size_t bm = i >> 4;
    int c = (int)(i & 15);
    int m = (int)(bm & 511);
    int p = c ^ (m & 7);
    const float* src = enc + bm * 128 + c * 8;
    float4 x0 = *(const float4*)(src);
    float4 x1 = *(const float4*)(src + 4);
    s16x8 h, l;
    fsplit8(x0, x1, h, l);
    *(s16x8*)(Eh + bm * 128 + p * 8) = h;
    *(s16x8*)(El + bm * 128 + p * 8) = l;
}

// score = AAFM@enc^T; wave = 16 n x 256 m (mh half); 32-m phases (16), 16 KB/buf
// dbuf -> 32 KB LDS, 3 blocks/CU. In-loop bias+tanh, fused softmax. Grid 2048.
__global__ __launch_bounds__(256, 3) void k_score(
        const float* __restrict__ AAFM,
        const unsigned short* __restrict__ Eh, const unsigned short* __restrict__ El,
        const float* __restrict__ cd, const float* __restrict__ ninf,
        const float* __restrict__ a2p, const float* __restrict__ lsp,
        float* __restrict__ out) {
    int o = blockIdx.x;
    int xcd = o & 7, j = o >> 3;       // j 0..255
    int b = ((j >> 4) << 3) + xcd;     // 16 b's per XCD
    int nb = j & 15;
    int n0 = nb * 32;
    int w = threadIdx.x >> 6, lane = threadIdx.x & 63;
    int row = lane & 15, kg = lane >> 4;
    int ng = w >> 1, mh = w & 1;
    __shared__ __align__(16) char lds[2][16384];  // dbuf x [hi|lo][32 m][256 B]
    __shared__ float redm[32][2];
    __shared__ float reds[32][2];
    float a2ls = a2p[0] * lsp[0];
    const float invs = 0.08838834764831845f;  // 1/sqrt(128)

    // A preload: 16 rows of packed AAFM (hi|lo<<16)
    const float* apk = AAFM + ((size_t)b * N + n0 + ng * 16 + row) * D + kg * 8;
    s16x8 ah[4], al[4];
#pragma unroll
    for (int es = 0; es < 4; es++) {
        float4 w0 = *(const float4*)(apk + es * 32);
        float4 w1 = *(const float4*)(apk + es * 32 + 4);
        unsigned u;
        u = __float_as_uint(w0.x); ah[es][0] = (short)(u & 0xffff); al[es][0] = (short)(u >> 16);
        u = __float_as_uint(w0.y); ah[es][1] = (short)(u & 0xffff); al[es][1] = (short)(u >> 16);
        u = __float_as_uint(w0.z); ah[es][2] = (short)(u & 0xffff); al[es][2] = (short)(u >> 16);
        u = __float_as_uint(w0.w); ah[es][3] = (short)(u & 0xffff); al[es][3] = (short)(u >> 16);
        u = __float_as_uint(w1.x); ah[es][4] = (short)(u & 0xffff); al[es][4] = (short)(u >> 16);
        u = __float_as_uint(w1.y); ah[es][5] = (short)(u & 0xffff); al[es][5] = (short)(u >> 16);
        u = __float_as_uint(w1.z); ah[es][6] = (short)(u & 0xffff); al[es][6] = (short)(u >> 16);
        u = __float_as_uint(w1.w); ah[es][7] = (short)(u & 0xffff); al[es][7] = (short)(u >> 16);
    }
    f32x4 acc[16];
#pragma unroll
    for (int i = 0; i < 16; i++) acc[i] = (f32x4)0.f;

#define STAGE_SC(buf, mc)                                                          \
    _Pragma("unroll")                                                              \
    for (int jv = 0; jv < 4; jv++) {                                               \
        int id = (w * 4 + jv) * 64 + lane;                                         \
        int arr = id >> 9, rem = id & 511;                                         \
        const unsigned short* gb = arr ? El : Eh;                                  \
        gload16((const char*)gb + ((size_t)b * M + (mc) * 32) * 256 + rem * 16,    \
                lds[buf] + arr * 8192 + rem * 16);                                 \
    }

    STAGE_SC(0, 0)
#pragma unroll
    for (int mc = 0; mc < 16; mc++) {
        int cur = mc & 1;
        __syncthreads();   // drains stages of buf[cur] (issued a full phase ago)
        int mloc = mh * 16 + row;
        int rbase = mloc * 256;
        int sw = mloc & 7;
#pragma unroll
        for (int es = 0; es < 4; es++) {
            int ph = (4 * es + kg) ^ sw;
            s16x8 bh = *(const s16x8*)(&lds[cur][rbase + ph * 16]);
            s16x8 bl = *(const s16x8*)(&lds[cur][8192 + rbase + ph * 16]);
            acc[mc] = MFMA16(ah[es], bh, acc[mc]);
            acc[mc] = MFMA16(al[es], bh, acc[mc]);
            acc[mc] = MFMA16(ah[es], bl, acc[mc]);
        }
        // this tile's cd/ninf loads
        float cdv[4], nfv[4];
#pragma unroll
        for (int r = 0; r < 4; r++) {
            size_t idx = ((size_t)b * N + n0 + ng * 16 + kg * 4 + r) * M
                       + (size_t)mc * 32 + mloc;
            cdv[r] = cd[idx];
            nfv[r] = ninf[idx];
        }
        if (mc < 15) STAGE_SC(cur ^ 1, mc + 1)
        // bias + tanh + mask
#pragma unroll
        for (int r = 0; r < 4; r++) {
            acc[mc][r] = 10.f * fast_tanh(fmaf(acc[mc][r], invs, -a2ls * cdv[r]))
                       + nfv[r];
        }
    }
    // softmax over m (cross-wave via mh halves)
    float mx[4], sm[4];
#pragma unroll
    for (int r = 0; r < 4; r++) {
        float m = acc[0][r];
#pragma unroll
        for (int a = 1; a < 16; a++) m = fmaxf(m, acc[a][r]);
#pragma unroll
        for (int s = 1; s < 16; s <<= 1) m = fmaxf(m, __shfl_xor(m, s, 64));
        mx[r] = m;
    }
    int rl = ng * 16 + kg * 4;
    if (row == 0) {
#pragma unroll
        for (int r = 0; r < 4; r++) redm[rl + r][mh] = mx[r];
    }
    __syncthreads();
#pragma unroll
    for (int r = 0; r < 4; r++) {
        float m = fmaxf(redm[rl + r][0], redm[rl + r][1]);
        float s = 0.f;
#pragma unroll
        for (int a = 0; a < 16; a++) {
            float e = __expf(acc[a][r] - m);
            acc[a][r] = e;
            s += e;
        }
#pragma unroll
        for (int sh = 1; sh < 16; sh <<= 1) s += __shfl_xor(s, sh, 64);
        sm[r] = s;
    }
    if (row == 0) {
#pragma unroll
        for (int r = 0; r < 4; r++) reds[rl + r][mh] = sm[r];
    }
    __syncthreads();
#pragma unroll
    for (int r = 0; r < 4; r++) {
        float inv = 1.f / (reds[rl + r][0] + reds[rl + r][1]);
        size_t ro = ((size_t)b * N + n0 + rl + r) * M;
#pragma unroll
        for (int a = 0; a < 16; a++) {
            out[ro + a * 32 + mh * 16 + row] = acc[a][r] * inv;
        }
    }
}

extern "C" void kernel_launch(void* const* d_in, const int* in_sizes, int n_in,
                              void* d_out, int out_size, void* d_ws, size_t ws_size,
                              hipStream_t stream) {
    const float* encl  = (const float*)d_in[0];
    const float* loadv = (const float*)d_in[1];
    const float* cdist = (const float*)d_in[2];
    const float* ls    = (const float*)d_in[3];
    const float* ninf  = (const float*)d_in[4];
    const float* enc   = (const float*)d_in[5];
    const float* Wq    = (const float*)d_in[6];
    const float* Wk    = (const float*)d_in[7];
    const float* Wv    = (const float*)d_in[8];
    const float* a1    = (const float*)d_in[9];
    const float* a2    = (const float*)d_in[10];
    char* ws = (char*)d_ws;
    unsigned short* EKT_hi  = (unsigned short*)(ws);
    unsigned short* EKT_lo  = (unsigned short*)(ws + 16777216);
    unsigned short* EKVT_hi = (unsigned short*)(ws + 33554432);
    unsigned short* EKVT_lo = (unsigned short*)(ws + 50331648);
    float*          SQ      = (float*)(ws + 67108864);
    unsigned short* Wk_hi   = (unsigned short*)(ws + 100663296);
    unsigned short* Wk_lo   = (unsigned short*)(ws + 100663296 + 32768);
    unsigned short* Wv_hi   = (unsigned short*)(ws + 100663296 + 65536);
    unsigned short* Wv_lo   = (unsigned short*)(ws + 100663296 + 98304);
    unsigned short* Wq_hi   = (unsigned short*)(ws + 100663296 + 131072);
    unsigned short* Wq_lo   = (unsigned short*)(ws + 100663296 + 163840);
    unsigned short* ENC_hi  = EKT_hi;   // reuse dead EKT region after k_numden
    unsigned short* ENC_lo  = EKT_lo;
    float* out = (float*)d_out;

    k_prep_w<<<192, 256, 0, stream>>>(Wk, Wv, Wq, Wk_hi, Wk_lo, Wv_hi, Wv_lo, Wq_hi, Wq_lo);
    k_kv<<<dim3(8, 128), 256, 0, stream>>>(enc, Wk_hi, Wk_lo, Wv_hi, Wv_lo,
                                           EKT_hi, EKT_lo, EKVT_hi, EKVT_lo);
    k_q<<<dim3(8, 128), 256, 0, stream>>>(encl, loadv, Wq, Wq_hi, Wq_lo, SQ);
    k_numden<<<1024, 256, 0, stream>>>(cdist, ninf, EKVT_hi, EKVT_lo,
                                       EKT_hi, EKT_lo, SQ, a1, ls);
    k_encsplit<<<4096, 256, 0, stream>>>(enc, ENC_hi, ENC_lo);
    k_score<<<2048, 256, 0, stream>>>(SQ, ENC_hi, ENC_lo, cdist, ninf, a2, ls, out);
}

// Round 8
// 369.337 us; speedup vs baseline: 1.1714x; 1.1714x over previous
//
#include <hip/hip_runtime.h>
#include <math.h>

#define B 128
#define N 512
#define M 512
#define D 128

typedef __attribute__((ext_vector_type(8))) short s16x8;
typedef __attribute__((ext_vector_type(4))) short s16x4;
typedef __attribute__((ext_vector_type(4))) float f32x4;

#define MFMA16(a, b, c) __builtin_amdgcn_mfma_f32_16x16x32_bf16(a, b, c, 0, 0, 0)

__device__ __forceinline__ void gload16(const void* g, void* l) {
    __builtin_amdgcn_global_load_lds(
        (const __attribute__((address_space(1))) unsigned int*)g,
        (__attribute__((address_space(3))) unsigned int*)l, 16, 0, 0);
}

__device__ __forceinline__ float fast_tanh(float x) {
    x = fminf(fmaxf(x, -15.f), 15.f);
    float E = __expf(2.f * x);
    return 1.f - 2.f / (E + 1.f);
}

// bf16 round-to-nearest-even (unbiased; bias cancellation in num/den ratio)
__device__ __forceinline__ unsigned short bf16rne(float x) {
    unsigned u = __float_as_uint(x);
    return (unsigned short)((u + 0x7FFF + ((u >> 16) & 1)) >> 16);
}

// Truncation split: x ~= hi + lo
__device__ __forceinline__ void fsplit(float x, short& h, short& l) {
    unsigned u = __float_as_uint(x);
    h = (short)(u >> 16);
    float fh = __uint_as_float(u & 0xffff0000u);
    l = (short)(__float_as_uint(x - fh) >> 16);
}

__device__ __forceinline__ void fsplit8(float4 x0, float4 x1, s16x8& h, s16x8& l) {
    short a, b;
    fsplit(x0.x, a, b); h[0] = a; l[0] = b;
    fsplit(x0.y, a, b); h[1] = a; l[1] = b;
    fsplit(x0.z, a, b); h[2] = a; l[2] = b;
    fsplit(x0.w, a, b); h[3] = a; l[3] = b;
    fsplit(x1.x, a, b); h[4] = a; l[4] = b;
    fsplit(x1.y, a, b); h[5] = a; l[5] = b;
    fsplit(x1.z, a, b); h[6] = a; l[6] = b;
    fsplit(x1.w, a, b); h[7] = a; l[7] = b;
}

// EB = exp(-a1ls*cd + ninf) for 8 elements, split to bf16 hi/lo
__device__ __forceinline__ void ebsplit(float4 c0, float4 c1, float4 f0, float4 f1,
                                        float a1ls, s16x8& ah, s16x8& al) {
    float4 e0, e1;
    e0.x = __expf(fmaf(-a1ls, c0.x, f0.x));
    e0.y = __expf(fmaf(-a1ls, c0.y, f0.y));
    e0.z = __expf(fmaf(-a1ls, c0.z, f0.z));
    e0.w = __expf(fmaf(-a1ls, c0.w, f0.w));
    e1.x = __expf(fmaf(-a1ls, c1.x, f1.x));
    e1.y = __expf(fmaf(-a1ls, c1.y, f1.y));
    e1.z = __expf(fmaf(-a1ls, c1.z, f1.z));
    e1.w = __expf(fmaf(-a1ls, c1.w, f1.w));
    fsplit8(e0, e1, ah, al);
}

__global__ void k_prep_w(const float* __restrict__ Wk, const float* __restrict__ Wv,
                         const float* __restrict__ Wq,
                         unsigned short* __restrict__ Wk_hi, unsigned short* __restrict__ Wk_lo,
                         unsigned short* __restrict__ Wv_hi, unsigned short* __restrict__ Wv_lo,
                         unsigned short* __restrict__ Wq_hi, unsigned short* __restrict__ Wq_lo) {
    int i = blockIdx.x * 256 + threadIdx.x;  // 0..49151
    short h, l;
    if (i < 16384) {
        fsplit(Wk[i], h, l); Wk_hi[i] = (unsigned short)h; Wk_lo[i] = (unsigned short)l;
    } else if (i < 32768) {
        int j = i - 16384;
        fsplit(Wv[j], h, l); Wv_hi[j] = (unsigned short)h; Wv_lo[j] = (unsigned short)l;
    } else {
        int j = i - 32768; int e = j >> 7, d = j & 127;
        fsplit(Wq[e * 129 + d], h, l); Wq_hi[j] = (unsigned short)h; Wq_lo[j] = (unsigned short)l;
    }
}

// k = enc@Wk^T, v = enc@Wv^T; store bf16-RNE EK, EK*V as [b][e][m],
// SWIZZLED: within each 32-m group, 8-m chunk c stored at c ^ (e&3).
__global__ __launch_bounds__(256) void k_kv(const float* __restrict__ enc,
        const unsigned short* __restrict__ Wk_hi, const unsigned short* __restrict__ Wk_lo,
        const unsigned short* __restrict__ Wv_hi, const unsigned short* __restrict__ Wv_lo,
        unsigned short* __restrict__ EKb, unsigned short* __restrict__ EKVb) {
    int b = blockIdx.y;
    int wave = threadIdx.x >> 6, lane = threadIdx.x & 63;
    int row = lane & 15, kg = lane >> 4;
    int m0 = blockIdx.x * 64 + wave * 16;
    f32x4 acc[16];
#pragma unroll
    for (int i = 0; i < 16; i++) acc[i] = (f32x4)0.f;
    const float* ap = enc + ((size_t)b * M + m0 + row) * D + kg * 8;
#pragma unroll
    for (int ks = 0; ks < 4; ks++) {
        float4 x0 = *(const float4*)(ap + ks * 32);
        float4 x1 = *(const float4*)(ap + ks * 32 + 4);
        s16x8 ah, al;
        fsplit8(x0, x1, ah, al);
        int wb = ks * 32 + kg * 8;
#pragma unroll
        for (int ct = 0; ct < 8; ct++) {
            int e = ct * 16 + row;
            s16x8 bh = *(const s16x8*)(Wk_hi + e * D + wb);
            s16x8 bl = *(const s16x8*)(Wk_lo + e * D + wb);
            acc[ct] = MFMA16(ah, bh, acc[ct]);
            acc[ct] = MFMA16(al, bh, acc[ct]);
            acc[ct] = MFMA16(ah, bl, acc[ct]);
            bh = *(const s16x8*)(Wv_hi + e * D + wb);
            bl = *(const s16x8*)(Wv_lo + e * D + wb);
            acc[8 + ct] = MFMA16(ah, bh, acc[8 + ct]);
            acc[8 + ct] = MFMA16(al, bh, acc[8 + ct]);
            acc[8 + ct] = MFMA16(ah, bl, acc[8 + ct]);
        }
    }
#pragma unroll
    for (int ct = 0; ct < 8; ct++) {
        int e = ct * 16 + row;
        s16x4 kb, vb;
#pragma unroll
        for (int r = 0; r < 4; r++) {
            float ek = __expf(acc[ct][r]);
            float ev = ek * acc[8 + ct][r];
            kb[r] = (short)bf16rne(ek);
            vb[r] = (short)bf16rne(ev);
        }
        int m = m0 + kg * 4;
        int chunk = (m & 31) >> 3;
        int p = chunk ^ (e & 3);
        size_t o = ((size_t)b * D + e) * M + (size_t)(m & ~31) + p * 8 + (m & 7);
        *(s16x4*)(EKb + o) = kb;
        *(s16x4*)(EKVb + o) = vb;
    }
}

// q = [encl, load]@Wq^T; SQ = sigmoid(q) f32 [b][n][e]
__global__ __launch_bounds__(256) void k_q(const float* __restrict__ encl,
        const float* __restrict__ loadv, const float* __restrict__ Wq,
        const unsigned short* __restrict__ Wq_hi, const unsigned short* __restrict__ Wq_lo,
        float* __restrict__ SQ) {
    int b = blockIdx.y;
    int wave = threadIdx.x >> 6, lane = threadIdx.x & 63;
    int row = lane & 15, kg = lane >> 4;
    int n0 = blockIdx.x * 64 + wave * 16;
    f32x4 acc[8];
#pragma unroll
    for (int i = 0; i < 8; i++) acc[i] = (f32x4)0.f;
    const float* ap = encl + ((size_t)b * N + n0 + row) * D + kg * 8;
#pragma unroll
    for (int ks = 0; ks < 4; ks++) {
        float4 x0 = *(const float4*)(ap + ks * 32);
        float4 x1 = *(const float4*)(ap + ks * 32 + 4);
        s16x8 ah, al;
        fsplit8(x0, x1, ah, al);
        int wb = ks * 32 + kg * 8;
#pragma unroll
        for (int ct = 0; ct < 8; ct++) {
            int e = ct * 16 + row;
            s16x8 bh = *(const s16x8*)(Wq_hi + e * D + wb);
            s16x8 bl = *(const s16x8*)(Wq_lo + e * D + wb);
            acc[ct] = MFMA16(ah, bh, acc[ct]);
            acc[ct] = MFMA16(al, bh, acc[ct]);
            acc[ct] = MFMA16(ah, bl, acc[ct]);
        }
    }
#pragma unroll
    for (int r = 0; r < 4; r++) {
        int n = n0 + kg * 4 + r;
        float lv = loadv[(size_t)b * N + n];
        size_t ro = ((size_t)b * N + n) * D;
#pragma unroll
        for (int ct = 0; ct < 8; ct++) {
            int e = ct * 16 + row;
            float q = acc[ct][r] + lv * Wq[e * 129 + 128];
            SQ[ro + e] = 1.f / (1.f + __expf(-q));
        }
    }
}

// num=EB@EKV, den=EB@EK. B-operands single bf16 (RNE). Block = 4 waves:
// wave = 32n x 64e (n-split 2 x e-split 2) -> block 64n x 128e. 16 phases of
// m=32; LDS 16 KB/buf dbuf = 32 KB -> 4 blocks/CU (grid 1024 XCD-bijective).
__global__ __launch_bounds__(256) void k_numden(
        const float* __restrict__ cd, const float* __restrict__ ninf,
        const unsigned short* __restrict__ EKVb, const unsigned short* __restrict__ EKb,
        float* __restrict__ SQ,
        const float* __restrict__ a1p, const float* __restrict__ lsp) {
    int o = blockIdx.x;
    int xcd = o & 7, j = o >> 3;       // j 0..127
    int b = ((j >> 3) << 3) + xcd;     // 16 b's per XCD
    int nb = j & 7;
    int w = threadIdx.x >> 6, lane = threadIdx.x & 63;
    int ns = w >> 1, eh = w & 1;
    int row = lane & 15, kg = lane >> 4;
    int n0 = nb * 64 + ns * 32;
    __shared__ __align__(16) char lds[2][16384];  // [2 arr][128 e][32 m x 2B]
    float a1ls = a1p[0] * lsp[0];
    const char* gEKV = (const char*)EKVb + (size_t)b * D * M * 2;
    const char* gEK  = (const char*)EKb  + (size_t)b * D * M * 2;
    f32x4 accN[2][4], accD[2][4];
#pragma unroll
    for (int s = 0; s < 2; s++)
#pragma unroll
        for (int i = 0; i < 4; i++) { accN[s][i] = (f32x4)0.f; accD[s][i] = (f32x4)0.f; }
    const float* cdp0 = cd + ((size_t)b * N + n0 + row) * M + kg * 8;
    const float* nfp0 = ninf + ((size_t)b * N + n0 + row) * M + kg * 8;
    const float* cdp1 = cdp0 + (size_t)16 * M;
    const float* nfp1 = nfp0 + (size_t)16 * M;
    // read base: e = eh*64 + ct*16 + row; swizzled chunk ph = kg ^ (row&3)
    int rbase = eh * 4096 + row * 64 + ((kg ^ (row & 3)) << 4);

// stage 16 KB: idx = jv*256 + tid in [0,1024); arr=idx>>9, e=(idx>>2)&127, c16=idx&3
#define STAGE_ND(buf, mt)                                                        \
    _Pragma("unroll")                                                            \
    for (int jv = 0; jv < 4; jv++) {                                             \
        int idx = jv * 256 + threadIdx.x;                                        \
        const char* gb = (idx >> 9) ? gEK : gEKV;                                \
        int rem = idx & 511;                                                     \
        gload16(gb + (size_t)(rem >> 2) * 1024 + (mt) * 64 + (rem & 3) * 16,     \
                (char*)lds + (buf) * 16384 + idx * 16);                          \
    }

    // prologue: A-regs for phase 0 (both sets), stage tile 0
    float4 c00 = *(const float4*)(cdp0), c01 = *(const float4*)(cdp0 + 4);
    float4 f00 = *(const float4*)(nfp0), f01 = *(const float4*)(nfp0 + 4);
    float4 c10 = *(const float4*)(cdp1), c11 = *(const float4*)(cdp1 + 4);
    float4 f10 = *(const float4*)(nfp1), f11 = *(const float4*)(nfp1 + 4);
    STAGE_ND(0, 0)

#pragma unroll 2
    for (int mt = 0; mt < 16; mt++) {
        int cur = mt & 1;
        __syncthreads();   // drains stages of buf[cur] (issued a full phase ago)
        s16x8 ah0, al0, ah1, al1;
        ebsplit(c00, c01, f00, f01, a1ls, ah0, al0);
        ebsplit(c10, c11, f10, f11, a1ls, ah1, al1);
        if (mt < 15) {
            int m = (mt + 1) * 32;
            c00 = *(const float4*)(cdp0 + m); c01 = *(const float4*)(cdp0 + m + 4);
            f00 = *(const float4*)(nfp0 + m); f01 = *(const float4*)(nfp0 + m + 4);
            c10 = *(const float4*)(cdp1 + m); c11 = *(const float4*)(cdp1 + m + 4);
            f10 = *(const float4*)(nfp1 + m); f11 = *(const float4*)(nfp1 + m + 4);
            STAGE_ND(cur ^ 1, mt + 1)
        }
        const char* L = (const char*)lds + cur * 16384;
#pragma unroll
        for (int ct = 0; ct < 4; ct++) {
            int ro = ct * 1024 + rbase;
            s16x8 bv = *(const s16x8*)(L + ro);           // EKV bf16
            s16x8 bk = *(const s16x8*)(L + 8192 + ro);    // EK bf16
            accN[0][ct] = MFMA16(ah0, bv, accN[0][ct]);
            accN[0][ct] = MFMA16(al0, bv, accN[0][ct]);
            accN[1][ct] = MFMA16(ah1, bv, accN[1][ct]);
            accN[1][ct] = MFMA16(al1, bv, accN[1][ct]);
            accD[0][ct] = MFMA16(ah0, bk, accD[0][ct]);
            accD[0][ct] = MFMA16(al0, bk, accD[0][ct]);
            accD[1][ct] = MFMA16(ah1, bk, accD[1][ct]);
            accD[1][ct] = MFMA16(al1, bk, accD[1][ct]);
        }
    }
#pragma unroll
    for (int s = 0; s < 2; s++) {
#pragma unroll
        for (int r = 0; r < 4; r++) {
            int n = n0 + s * 16 + kg * 4 + r;
            size_t ro = ((size_t)b * N + n) * D;
#pragma unroll
            for (int ct = 0; ct < 4; ct++) {
                int e = eh * 64 + ct * 16 + row;
                float num = accN[s][ct][r], den = accD[s][ct][r];
                float ww = (den != 0.f) ? num / den : 0.f;
                float aafm = SQ[ro + e] * ww;
                unsigned u = __float_as_uint(aafm);
                unsigned hi = u >> 16;
                float fh = __uint_as_float(u & 0xffff0000u);
                unsigned lo = __float_as_uint(aafm - fh) >> 16;
                SQ[ro + e] = __uint_as_float(hi | (lo << 16));
            }
        }
    }
}

// Split enc -> bf16 hi/lo [b][m][128e], SWIZZLED: 8-e chunk c at c ^ (m&7)
__global__ void k_encsplit(const float* __restrict__ enc,
                           unsigned short* __restrict__ Eh, unsigned short* __restrict__ El) {
    size_t i = (size_t)blockIdx.x * 256 + threadIdx.x;   // chunk id
    size_t bm = i >> 4;
    int c = (int)(i & 15);
    int m = (int)(bm & 511);
    int p = c ^ (m & 7);
    const float* src = enc + bm * 128 + c * 8;
    float4 x0 = *(const float4*)(src);
    float4 x1 = *(const float4*)(src + 4);
    s16x8 h, l;
    fsplit8(x0, x1, h, l);
    *(s16x8*)(Eh + bm * 128 + p * 8) = h;
    *(s16x8*)(El + bm * 128 + p * 8) = l;
}

// score = AAFM@enc^T; wave = 16 n x 256 m (mh half); 32-m phases (16), 16 KB/buf
// dbuf -> 32 KB LDS. In-loop bias+tanh, fused softmax. Grid 2048 XCD-bijective.
__global__ __launch_bounds__(256) void k_score(
        const float* __restrict__ AAFM,
        const unsigned short* __restrict__ Eh, const unsigned short* __restrict__ El,
        const float* __restrict__ cd, const float* __restrict__ ninf,
        const float* __restrict__ a2p, const float* __restrict__ lsp,
        float* __restrict__ out) {
    int o = blockIdx.x;
    int xcd = o & 7, j = o >> 3;       // j 0..255
    int b = ((j >> 4) << 3) + xcd;     // 16 b's per XCD
    int nb = j & 15;
    int n0 = nb * 32;
    int w = threadIdx.x >> 6, lane = threadIdx.x & 63;
    int row = lane & 15, kg = lane >> 4;
    int ng = w >> 1, mh = w & 1;
    __shared__ __align__(16) char lds[2][16384];  // dbuf x [hi|lo][32 m][256 B]
    __shared__ float redm[32][2];
    __shared__ float reds[32][2];
    float a2ls = a2p[0] * lsp[0];
    const float invs = 0.08838834764831845f;  // 1/sqrt(128)

    // A preload: 16 rows of packed AAFM (hi|lo<<16)
    const float* apk = AAFM + ((size_t)b * N + n0 + ng * 16 + row) * D + kg * 8;
    s16x8 ah[4], al[4];
#pragma unroll
    for (int es = 0; es < 4; es++) {
        float4 w0 = *(const float4*)(apk + es * 32);
        float4 w1 = *(const float4*)(apk + es * 32 + 4);
        unsigned u;
        u = __float_as_uint(w0.x); ah[es][0] = (short)(u & 0xffff); al[es][0] = (short)(u >> 16);
        u = __float_as_uint(w0.y); ah[es][1] = (short)(u & 0xffff); al[es][1] = (short)(u >> 16);
        u = __float_as_uint(w0.z); ah[es][2] = (short)(u & 0xffff); al[es][2] = (short)(u >> 16);
        u = __float_as_uint(w0.w); ah[es][3] = (short)(u & 0xffff); al[es][3] = (short)(u >> 16);
        u = __float_as_uint(w1.x); ah[es][4] = (short)(u & 0xffff); al[es][4] = (short)(u >> 16);
        u = __float_as_uint(w1.y); ah[es][5] = (short)(u & 0xffff); al[es][5] = (short)(u >> 16);
        u = __float_as_uint(w1.z); ah[es][6] = (short)(u & 0xffff); al[es][6] = (short)(u >> 16);
        u = __float_as_uint(w1.w); ah[es][7] = (short)(u & 0xffff); al[es][7] = (short)(u >> 16);
    }
    f32x4 acc[16];
#pragma unroll
    for (int i = 0; i < 16; i++) acc[i] = (f32x4)0.f;

#define STAGE_SC(buf, mc)                                                          \
    _Pragma("unroll")                                                              \
    for (int jv = 0; jv < 4; jv++) {                                               \
        int id = (w * 4 + jv) * 64 + lane;                                         \
        int arr = id >> 9, rem = id & 511;                                         \
        const unsigned short* gb = arr ? El : Eh;                                  \
        gload16((const char*)gb + ((size_t)b * M + (mc) * 32) * 256 + rem * 16,    \
                (char*)lds + (buf) * 16384 + arr * 8192 + rem * 16);               \
    }

    STAGE_SC(0, 0)
#pragma unroll
    for (int mc = 0; mc < 16; mc++) {
        int cur = mc & 1;
        __syncthreads();   // drains stages of buf[cur] (issued a full phase ago)
        int mloc = mh * 16 + row;
        int rbase = mloc * 256;
        int sw = mloc & 7;
        const char* L = (const char*)lds + cur * 16384;
#pragma unroll
        for (int es = 0; es < 4; es++) {
            int ph = (4 * es + kg) ^ sw;
            s16x8 bh = *(const s16x8*)(L + rbase + ph * 16);
            s16x8 bl = *(const s16x8*)(L + 8192 + rbase + ph * 16);
            acc[mc] = MFMA16(ah[es], bh, acc[mc]);
            acc[mc] = MFMA16(al[es], bh, acc[mc]);
            acc[mc] = MFMA16(ah[es], bl, acc[mc]);
        }
        // this tile's cd/ninf loads
        float cdv[4], nfv[4];
#pragma unroll
        for (int r = 0; r < 4; r++) {
            size_t idx = ((size_t)b * N + n0 + ng * 16 + kg * 4 + r) * M
                       + (size_t)mc * 32 + mloc;
            cdv[r] = cd[idx];
            nfv[r] = ninf[idx];
        }
        if (mc < 15) STAGE_SC(cur ^ 1, mc + 1)
        // bias + tanh + mask
#pragma unroll
        for (int r = 0; r < 4; r++) {
            acc[mc][r] = 10.f * fast_tanh(fmaf(acc[mc][r], invs, -a2ls * cdv[r]))
                       + nfv[r];
        }
    }
    // softmax over m (cross-wave via mh halves)
    float mx[4], sm[4];
#pragma unroll
    for (int r = 0; r < 4; r++) {
        float m = acc[0][r];
#pragma unroll
        for (int a = 1; a < 16; a++) m = fmaxf(m, acc[a][r]);
#pragma unroll
        for (int s = 1; s < 16; s <<= 1) m = fmaxf(m, __shfl_xor(m, s, 64));
        mx[r] = m;
    }
    int rl = ng * 16 + kg * 4;
    if (row == 0) {
#pragma unroll
        for (int r = 0; r < 4; r++) redm[rl + r][mh] = mx[r];
    }
    __syncthreads();
#pragma unroll
    for (int r = 0; r < 4; r++) {
        float m = fmaxf(redm[rl + r][0], redm[rl + r][1]);
        float s = 0.f;
#pragma unroll
        for (int a = 0; a < 16; a++) {
            float e = __expf(acc[a][r] - m);
            acc[a][r] = e;
            s += e;
        }
#pragma unroll
        for (int sh = 1; sh < 16; sh <<= 1) s += __shfl_xor(s, sh, 64);
        sm[r] = s;
    }
    if (row == 0) {
#pragma unroll
        for (int r = 0; r < 4; r++) reds[rl + r][mh] = sm[r];
    }
    __syncthreads();
#pragma unroll
    for (int r = 0; r < 4; r++) {
        float inv = 1.f / (reds[rl + r][0] + reds[rl + r][1]);
        size_t ro = ((size_t)b * N + n0 + rl + r) * M;
#pragma unroll
        for (int a = 0; a < 16; a++) {
            out[ro + a * 32 + mh * 16 + row] = acc[a][r] * inv;
        }
    }
}

extern "C" void kernel_launch(void* const* d_in, const int* in_sizes, int n_in,
                              void* d_out, int out_size, void* d_ws, size_t ws_size,
                              hipStream_t stream) {
    const float* encl  = (const float*)d_in[0];
    const float* loadv = (const float*)d_in[1];
    const float* cdist = (const float*)d_in[2];
    const float* ls    = (const float*)d_in[3];
    const float* ninf  = (const float*)d_in[4];
    const float* enc   = (const float*)d_in[5];
    const float* Wq    = (const float*)d_in[6];
    const float* Wk    = (const float*)d_in[7];
    const float* Wv    = (const float*)d_in[8];
    const float* a1    = (const float*)d_in[9];
    const float* a2    = (const float*)d_in[10];
    char* ws = (char*)d_ws;
    unsigned short* EKb     = (unsigned short*)(ws);                 // 33.5 MB
    unsigned short* EKVb    = (unsigned short*)(ws + 33554432);      // 33.5 MB
    float*          SQ      = (float*)(ws + 67108864);               // 33.5 MB
    unsigned short* Wk_hi   = (unsigned short*)(ws + 100663296);
    unsigned short* Wk_lo   = (unsigned short*)(ws + 100663296 + 32768);
    unsigned short* Wv_hi   = (unsigned short*)(ws + 100663296 + 65536);
    unsigned short* Wv_lo   = (unsigned short*)(ws + 100663296 + 98304);
    unsigned short* Wq_hi   = (unsigned short*)(ws + 100663296 + 131072);
    unsigned short* Wq_lo   = (unsigned short*)(ws + 100663296 + 163840);
    unsigned short* ENC_hi  = EKb;    // reuse dead EK/EKV regions after k_numden
    unsigned short* ENC_lo  = EKVb;
    float* out = (float*)d_out;

    k_prep_w<<<192, 256, 0, stream>>>(Wk, Wv, Wq, Wk_hi, Wk_lo, Wv_hi, Wv_lo, Wq_hi, Wq_lo);
    k_kv<<<dim3(8, 128), 256, 0, stream>>>(enc, Wk_hi, Wk_lo, Wv_hi, Wv_lo, EKb, EKVb);
    k_q<<<dim3(8, 128), 256, 0, stream>>>(encl, loadv, Wq, Wq_hi, Wq_lo, SQ);
    k_numden<<<1024, 256, 0, stream>>>(cdist, ninf, EKVb, EKb, SQ, a1, ls);
    k_encsplit<<<4096, 256, 0, stream>>>(enc, ENC_hi, ENC_lo);
    k_score<<<2048, 256, 0, stream>>>(SQ, ENC_hi, ENC_lo, cdist, ninf, a2, ls, out);
}

// Round 9
// 358.319 us; speedup vs baseline: 1.2074x; 1.0307x over previous
//
#include <hip/hip_runtime.h>
#include <math.h>

#define B 128
#define N 512
#define M 512
#define D 128

typedef __attribute__((ext_vector_type(8))) short s16x8;
typedef __attribute__((ext_vector_type(4))) short s16x4;
typedef __attribute__((ext_vector_type(4))) float f32x4;

#define MFMA16(a, b, c) __builtin_amdgcn_mfma_f32_16x16x32_bf16(a, b, c, 0, 0, 0)

#define VMCNT4()  asm volatile("s_waitcnt vmcnt(4)" ::: "memory")
#define VMCNT8()  asm volatile("s_waitcnt vmcnt(8)" ::: "memory")
#define VMCNT12() asm volatile("s_waitcnt vmcnt(12)" ::: "memory")

__device__ __forceinline__ void gload16(const void* g, void* l) {
    __builtin_amdgcn_global_load_lds(
        (const __attribute__((address_space(1))) unsigned int*)g,
        (__attribute__((address_space(3))) unsigned int*)l, 16, 0, 0);
}

__device__ __forceinline__ float fast_tanh(float x) {
    x = fminf(fmaxf(x, -15.f), 15.f);
    float E = __expf(2.f * x);
    return 1.f - 2.f / (E + 1.f);
}

// bf16 round-to-nearest-even (unbiased; bias cancellation in num/den ratio)
__device__ __forceinline__ unsigned short bf16rne(float x) {
    unsigned u = __float_as_uint(x);
    return (unsigned short)((u + 0x7FFF + ((u >> 16) & 1)) >> 16);
}

// Truncation split: x ~= hi + lo
__device__ __forceinline__ void fsplit(float x, short& h, short& l) {
    unsigned u = __float_as_uint(x);
    h = (short)(u >> 16);
    float fh = __uint_as_float(u & 0xffff0000u);
    l = (short)(__float_as_uint(x - fh) >> 16);
}

__device__ __forceinline__ void fsplit8(float4 x0, float4 x1, s16x8& h, s16x8& l) {
    short a, b;
    fsplit(x0.x, a, b); h[0] = a; l[0] = b;
    fsplit(x0.y, a, b); h[1] = a; l[1] = b;
    fsplit(x0.z, a, b); h[2] = a; l[2] = b;
    fsplit(x0.w, a, b); h[3] = a; l[3] = b;
    fsplit(x1.x, a, b); h[4] = a; l[4] = b;
    fsplit(x1.y, a, b); h[5] = a; l[5] = b;
    fsplit(x1.z, a, b); h[6] = a; l[6] = b;
    fsplit(x1.w, a, b); h[7] = a; l[7] = b;
}

// EB = exp(-a1ls*cd + ninf) for 8 elements, split to bf16 hi/lo
__device__ __forceinline__ void ebsplit(float4 c0, float4 c1, float4 f0, float4 f1,
                                        float a1ls, s16x8& ah, s16x8& al) {
    float4 e0, e1;
    e0.x = __expf(fmaf(-a1ls, c0.x, f0.x));
    e0.y = __expf(fmaf(-a1ls, c0.y, f0.y));
    e0.z = __expf(fmaf(-a1ls, c0.z, f0.z));
    e0.w = __expf(fmaf(-a1ls, c0.w, f0.w));
    e1.x = __expf(fmaf(-a1ls, c1.x, f1.x));
    e1.y = __expf(fmaf(-a1ls, c1.y, f1.y));
    e1.z = __expf(fmaf(-a1ls, c1.z, f1.z));
    e1.w = __expf(fmaf(-a1ls, c1.w, f1.w));
    fsplit8(e0, e1, ah, al);
}

__global__ void k_prep_w(const float* __restrict__ Wk, const float* __restrict__ Wv,
                         const float* __restrict__ Wq,
                         unsigned short* __restrict__ Wk_hi, unsigned short* __restrict__ Wk_lo,
                         unsigned short* __restrict__ Wv_hi, unsigned short* __restrict__ Wv_lo,
                         unsigned short* __restrict__ Wq_hi, unsigned short* __restrict__ Wq_lo) {
    int i = blockIdx.x * 256 + threadIdx.x;  // 0..49151
    short h, l;
    if (i < 16384) {
        fsplit(Wk[i], h, l); Wk_hi[i] = (unsigned short)h; Wk_lo[i] = (unsigned short)l;
    } else if (i < 32768) {
        int j = i - 16384;
        fsplit(Wv[j], h, l); Wv_hi[j] = (unsigned short)h; Wv_lo[j] = (unsigned short)l;
    } else {
        int j = i - 32768; int e = j >> 7, d = j & 127;
        fsplit(Wq[e * 129 + d], h, l); Wq_hi[j] = (unsigned short)h; Wq_lo[j] = (unsigned short)l;
    }
}

// k = enc@Wk^T, v = enc@Wv^T; store bf16-RNE EK, EK*V as [b][e][m],
// SWIZZLED: within each 32-m group, 8-m chunk c stored at c ^ (e&3).
__global__ __launch_bounds__(256) void k_kv(const float* __restrict__ enc,
        const unsigned short* __restrict__ Wk_hi, const unsigned short* __restrict__ Wk_lo,
        const unsigned short* __restrict__ Wv_hi, const unsigned short* __restrict__ Wv_lo,
        unsigned short* __restrict__ EKb, unsigned short* __restrict__ EKVb) {
    int b = blockIdx.y;
    int wave = threadIdx.x >> 6, lane = threadIdx.x & 63;
    int row = lane & 15, kg = lane >> 4;
    int m0 = blockIdx.x * 64 + wave * 16;
    f32x4 acc[16];
#pragma unroll
    for (int i = 0; i < 16; i++) acc[i] = (f32x4)0.f;
    const float* ap = enc + ((size_t)b * M + m0 + row) * D + kg * 8;
#pragma unroll
    for (int ks = 0; ks < 4; ks++) {
        float4 x0 = *(const float4*)(ap + ks * 32);
        float4 x1 = *(const float4*)(ap + ks * 32 + 4);
        s16x8 ah, al;
        fsplit8(x0, x1, ah, al);
        int wb = ks * 32 + kg * 8;
#pragma unroll
        for (int ct = 0; ct < 8; ct++) {
            int e = ct * 16 + row;
            s16x8 bh = *(const s16x8*)(Wk_hi + e * D + wb);
            s16x8 bl = *(const s16x8*)(Wk_lo + e * D + wb);
            acc[ct] = MFMA16(ah, bh, acc[ct]);
            acc[ct] = MFMA16(al, bh, acc[ct]);
            acc[ct] = MFMA16(ah, bl, acc[ct]);
            bh = *(const s16x8*)(Wv_hi + e * D + wb);
            bl = *(const s16x8*)(Wv_lo + e * D + wb);
            acc[8 + ct] = MFMA16(ah, bh, acc[8 + ct]);
            acc[8 + ct] = MFMA16(al, bh, acc[8 + ct]);
            acc[8 + ct] = MFMA16(ah, bl, acc[8 + ct]);
        }
    }
#pragma unroll
    for (int ct = 0; ct < 8; ct++) {
        int e = ct * 16 + row;
        s16x4 kb, vb;
#pragma unroll
        for (int r = 0; r < 4; r++) {
            float ek = __expf(acc[ct][r]);
            float ev = ek * acc[8 + ct][r];
            kb[r] = (short)bf16rne(ek);
            vb[r] = (short)bf16rne(ev);
        }
        int m = m0 + kg * 4;
        int chunk = (m & 31) >> 3;
        int p = chunk ^ (e & 3);
        size_t o = ((size_t)b * D + e) * M + (size_t)(m & ~31) + p * 8 + (m & 7);
        *(s16x4*)(EKb + o) = kb;
        *(s16x4*)(EKVb + o) = vb;
    }
}

// q = [encl, load]@Wq^T; SQ = sigmoid(q) f32 [b][n][e]
__global__ __launch_bounds__(256) void k_q(const float* __restrict__ encl,
        const float* __restrict__ loadv, const float* __restrict__ Wq,
        const unsigned short* __restrict__ Wq_hi, const unsigned short* __restrict__ Wq_lo,
        float* __restrict__ SQ) {
    int b = blockIdx.y;
    int wave = threadIdx.x >> 6, lane = threadIdx.x & 63;
    int row = lane & 15, kg = lane >> 4;
    int n0 = blockIdx.x * 64 + wave * 16;
    f32x4 acc[8];
#pragma unroll
    for (int i = 0; i < 8; i++) acc[i] = (f32x4)0.f;
    const float* ap = encl + ((size_t)b * N + n0 + row) * D + kg * 8;
#pragma unroll
    for (int ks = 0; ks < 4; ks++) {
        float4 x0 = *(const float4*)(ap + ks * 32);
        float4 x1 = *(const float4*)(ap + ks * 32 + 4);
        s16x8 ah, al;
        fsplit8(x0, x1, ah, al);
        int wb = ks * 32 + kg * 8;
#pragma unroll
        for (int ct = 0; ct < 8; ct++) {
            int e = ct * 16 + row;
            s16x8 bh = *(const s16x8*)(Wq_hi + e * D + wb);
            s16x8 bl = *(const s16x8*)(Wq_lo + e * D + wb);
            acc[ct] = MFMA16(ah, bh, acc[ct]);
            acc[ct] = MFMA16(al, bh, acc[ct]);
            acc[ct] = MFMA16(ah, bl, acc[ct]);
        }
    }
#pragma unroll
    for (int r = 0; r < 4; r++) {
        int n = n0 + kg * 4 + r;
        float lv = loadv[(size_t)b * N + n];
        size_t ro = ((size_t)b * N + n) * D;
#pragma unroll
        for (int ct = 0; ct < 8; ct++) {
            int e = ct * 16 + row;
            float q = acc[ct][r] + lv * Wq[e * 129 + 128];
            SQ[ro + e] = 1.f / (1.f + __expf(-q));
        }
    }
}

// num=EB@EKV, den=EB@EK. B single bf16 (RNE). Triple-buffered LDS (3x16KB),
// counted vmcnt + raw s_barrier (T4: never drain to 0 in loop). Stage 2 ahead,
// A-regs 1 ahead. 16 phases of m=32. Grid 1024 XCD-bijective, 3 blocks/CU.
__global__ __launch_bounds__(256, 3) void k_numden(
        const float* __restrict__ cd, const float* __restrict__ ninf,
        const unsigned short* __restrict__ EKVb, const unsigned short* __restrict__ EKb,
        float* __restrict__ SQ,
        const float* __restrict__ a1p, const float* __restrict__ lsp) {
    int o = blockIdx.x;
    int xcd = o & 7, j = o >> 3;       // j 0..127
    int b = ((j >> 3) << 3) + xcd;     // 16 b's per XCD
    int nb = j & 7;
    int w = threadIdx.x >> 6, lane = threadIdx.x & 63;
    int ns = w >> 1, eh = w & 1;
    int row = lane & 15, kg = lane >> 4;
    int n0 = nb * 64 + ns * 32;
    __shared__ __align__(16) char lds[3][16384];  // 3-buf x [2 arr][128 e][32 m x 2B]
    float a1ls = a1p[0] * lsp[0];
    const char* gEKV = (const char*)EKVb + (size_t)b * D * M * 2;
    const char* gEK  = (const char*)EKb  + (size_t)b * D * M * 2;
    f32x4 accN[2][4], accD[2][4];
#pragma unroll
    for (int s = 0; s < 2; s++)
#pragma unroll
        for (int i = 0; i < 4; i++) { accN[s][i] = (f32x4)0.f; accD[s][i] = (f32x4)0.f; }
    const float* cdp0 = cd + ((size_t)b * N + n0 + row) * M + kg * 8;
    const float* nfp0 = ninf + ((size_t)b * N + n0 + row) * M + kg * 8;
    const float* cdp1 = cdp0 + (size_t)16 * M;
    const float* nfp1 = nfp0 + (size_t)16 * M;
    // read base: e = eh*64 + ct*16 + row; swizzled chunk ph = kg ^ (row&3)
    int rbase = eh * 4096 + row * 64 + ((kg ^ (row & 3)) << 4);

// stage 16 KB: idx = jv*256 + tid in [0,1024); arr=idx>>9, e=(idx>>2)&127, c16=idx&3
#define STAGE_ND(ldsbase, mt)                                                    \
    _Pragma("unroll")                                                            \
    for (int jv = 0; jv < 4; jv++) {                                             \
        int idx = jv * 256 + threadIdx.x;                                        \
        const char* gb = (idx >> 9) ? gEK : gEKV;                                \
        int rem = idx & 511;                                                     \
        gload16(gb + (size_t)(rem >> 2) * 1024 + (size_t)(mt) * 64 + (rem & 3) * 16, \
                (char*)(ldsbase) + idx * 16);                                    \
    }

    // prologue: A-regs for phase 0 (both sets), stage tiles 0 and 1
    float4 c00 = *(const float4*)(cdp0), c01 = *(const float4*)(cdp0 + 4);
    float4 f00 = *(const float4*)(nfp0), f01 = *(const float4*)(nfp0 + 4);
    float4 c10 = *(const float4*)(cdp1), c11 = *(const float4*)(cdp1 + 4);
    float4 f10 = *(const float4*)(nfp1), f11 = *(const float4*)(nfp1 + 4);
    STAGE_ND((char*)lds, 0)
    STAGE_ND((char*)lds + 16384, 1)

#pragma unroll
    for (int mt = 0; mt < 16; mt++) {
        // counted waits: younger-than-stage(mt) = A(mt)[8] + stage(mt+1)[4]
        if (mt == 0) { VMCNT4(); } else if (mt == 15) { VMCNT8(); } else { VMCNT12(); }
        __builtin_amdgcn_s_barrier();
        __builtin_amdgcn_sched_barrier(0);
        // issue next phase's A loads (stay in flight across next barrier)
        float4 nc00, nc01, nf00, nf01, nc10, nc11, nf10, nf11;
        if (mt < 15) {
            int m = (mt + 1) * 32;
            nc00 = *(const float4*)(cdp0 + m); nc01 = *(const float4*)(cdp0 + m + 4);
            nf00 = *(const float4*)(nfp0 + m); nf01 = *(const float4*)(nfp0 + m + 4);
            nc10 = *(const float4*)(cdp1 + m); nc11 = *(const float4*)(cdp1 + m + 4);
            nf10 = *(const float4*)(nfp1 + m); nf11 = *(const float4*)(nfp1 + m + 4);
        }
        // stage tile mt+2 (2 phases of latency cover)
        if (mt < 14) STAGE_ND((char*)lds + ((mt + 2) % 3) * 16384, mt + 2)
        s16x8 ah0, al0, ah1, al1;
        ebsplit(c00, c01, f00, f01, a1ls, ah0, al0);
        ebsplit(c10, c11, f10, f11, a1ls, ah1, al1);
        const char* L = (const char*)lds + (mt % 3) * 16384;
#pragma unroll
        for (int ct = 0; ct < 4; ct++) {
            int ro = ct * 1024 + rbase;
            s16x8 bv = *(const s16x8*)(L + ro);           // EKV bf16
            s16x8 bk = *(const s16x8*)(L + 8192 + ro);    // EK bf16
            accN[0][ct] = MFMA16(ah0, bv, accN[0][ct]);
            accN[0][ct] = MFMA16(al0, bv, accN[0][ct]);
            accN[1][ct] = MFMA16(ah1, bv, accN[1][ct]);
            accN[1][ct] = MFMA16(al1, bv, accN[1][ct]);
            accD[0][ct] = MFMA16(ah0, bk, accD[0][ct]);
            accD[0][ct] = MFMA16(al0, bk, accD[0][ct]);
            accD[1][ct] = MFMA16(ah1, bk, accD[1][ct]);
            accD[1][ct] = MFMA16(al1, bk, accD[1][ct]);
        }
        if (mt < 15) {
            c00 = nc00; c01 = nc01; f00 = nf00; f01 = nf01;
            c10 = nc10; c11 = nc11; f10 = nf10; f11 = nf11;
        }
    }
#pragma unroll
    for (int s = 0; s < 2; s++) {
#pragma unroll
        for (int r = 0; r < 4; r++) {
            int n = n0 + s * 16 + kg * 4 + r;
            size_t ro = ((size_t)b * N + n) * D;
#pragma unroll
            for (int ct = 0; ct < 4; ct++) {
                int e = eh * 64 + ct * 16 + row;
                float num = accN[s][ct][r], den = accD[s][ct][r];
                float ww = (den != 0.f) ? num / den : 0.f;
                float aafm = SQ[ro + e] * ww;
                unsigned u = __float_as_uint(aafm);
                unsigned hi = u >> 16;
                float fh = __uint_as_float(u & 0xffff0000u);
                unsigned lo = __float_as_uint(aafm - fh) >> 16;
                SQ[ro + e] = __uint_as_float(hi | (lo << 16));
            }
        }
    }
}

// Split enc -> bf16 hi/lo [b][m][128e], SWIZZLED: 8-e chunk c at c ^ (m&7)
__global__ void k_encsplit(const float* __restrict__ enc,
                           unsigned short* __restrict__ Eh, unsigned short* __restrict__ El) {
    size_t i = (size_t)blockIdx.x * 256 + threadIdx.x;   // chunk id
    size_t bm = i >> 4;
    int c = (int)(i & 15);
    int m = (int)(bm & 511);
    int p = c ^ (m & 7);
    const float* src = enc + bm * 128 + c * 8;
    float4 x0 = *(const float4*)(src);
    float4 x1 = *(const float4*)(src + 4);
    s16x8 h, l;
    fsplit8(x0, x1, h, l);
    *(s16x8*)(Eh + bm * 128 + p * 8) = h;
    *(s16x8*)(El + bm * 128 + p * 8) = l;
}

// score = AAFM@enc^T; triple-buffered staging + counted vmcnt + raw s_barrier;
// cd/ninf register-prefetched 1 phase ahead; in-loop bias+tanh; fused softmax.
// Grid 2048 XCD-bijective, 3 blocks/CU.
__global__ __launch_bounds__(256, 3) void k_score(
        const float* __restrict__ AAFM,
        const unsigned short* __restrict__ Eh, const unsigned short* __restrict__ El,
        const float* __restrict__ cd, const float* __restrict__ ninf,
        const float* __restrict__ a2p, const float* __restrict__ lsp,
        float* __restrict__ out) {
    int o = blockIdx.x;
    int xcd = o & 7, j = o >> 3;       // j 0..255
    int b = ((j >> 4) << 3) + xcd;     // 16 b's per XCD
    int nb = j & 15;
    int n0 = nb * 32;
    int w = threadIdx.x >> 6, lane = threadIdx.x & 63;
    int row = lane & 15, kg = lane >> 4;
    int ng = w >> 1, mh = w & 1;
    __shared__ __align__(16) char lds[3][16384];  // 3-buf x [hi|lo][32 m][256 B]
    __shared__ float redm[32][2];
    __shared__ float reds[32][2];
    float a2ls = a2p[0] * lsp[0];
    const float invs = 0.08838834764831845f;  // 1/sqrt(128)

    // A preload: 16 rows of packed AAFM (hi|lo<<16)
    const float* apk = AAFM + ((size_t)b * N + n0 + ng * 16 + row) * D + kg * 8;
    s16x8 ah[4], al[4];
#pragma unroll
    for (int es = 0; es < 4; es++) {
        float4 w0 = *(const float4*)(apk + es * 32);
        float4 w1 = *(const float4*)(apk + es * 32 + 4);
        unsigned u;
        u = __float_as_uint(w0.x); ah[es][0] = (short)(u & 0xffff); al[es][0] = (short)(u >> 16);
        u = __float_as_uint(w0.y); ah[es][1] = (short)(u & 0xffff); al[es][1] = (short)(u >> 16);
        u = __float_as_uint(w0.z); ah[es][2] = (short)(u & 0xffff); al[es][2] = (short)(u >> 16);
        u = __float_as_uint(w0.w); ah[es][3] = (short)(u & 0xffff); al[es][3] = (short)(u >> 16);
        u = __float_as_uint(w1.x); ah[es][4] = (short)(u & 0xffff); al[es][4] = (short)(u >> 16);
        u = __float_as_uint(w1.y); ah[es][5] = (short)(u & 0xffff); al[es][5] = (short)(u >> 16);
        u = __float_as_uint(w1.z); ah[es][6] = (short)(u & 0xffff); al[es][6] = (short)(u >> 16);
        u = __float_as_uint(w1.w); ah[es][7] = (short)(u & 0xffff); al[es][7] = (short)(u >> 16);
    }
    f32x4 acc[16];
#pragma unroll
    for (int i = 0; i < 16; i++) acc[i] = (f32x4)0.f;

    int mloc = mh * 16 + row;
    int rbase = mloc * 256;
    int sw = mloc & 7;
    size_t rowidx[4];
#pragma unroll
    for (int r = 0; r < 4; r++)
        rowidx[r] = ((size_t)b * N + n0 + ng * 16 + kg * 4 + r) * M;

#define STAGE_SC(ldsbase, mc)                                                      \
    _Pragma("unroll")                                                              \
    for (int jv = 0; jv < 4; jv++) {                                               \
        int id = (w * 4 + jv) * 64 + lane;                                         \
        int arr = id >> 9, rem = id & 511;                                         \
        const unsigned short* gb = arr ? El : Eh;                                  \
        gload16((const char*)gb + ((size_t)b * M + (size_t)(mc) * 32) * 256 + rem * 16, \
                (char*)(ldsbase) + arr * 8192 + rem * 16);                         \
    }

    // prologue: cd/ninf for tile 0, stage tiles 0 and 1
    float cdv[4], nfv[4];
#pragma unroll
    for (int r = 0; r < 4; r++) {
        cdv[r] = cd[rowidx[r] + mloc];
        nfv[r] = ninf[rowidx[r] + mloc];
    }
    STAGE_SC((char*)lds, 0)
    STAGE_SC((char*)lds + 16384, 1)

#pragma unroll
    for (int mc = 0; mc < 16; mc++) {
        // counted waits: younger-than-stage(mc) = cdnf(mc)[8] + stage(mc+1)[4]
        if (mc == 0) { VMCNT4(); } else if (mc == 15) { VMCNT8(); } else { VMCNT12(); }
        __builtin_amdgcn_s_barrier();
        __builtin_amdgcn_sched_barrier(0);
        // issue next tile's cd/ninf loads
        float ncd[4], nnf[4];
        if (mc < 15) {
#pragma unroll
            for (int r = 0; r < 4; r++) {
                ncd[r] = cd[rowidx[r] + (size_t)(mc + 1) * 32 + mloc];
                nnf[r] = ninf[rowidx[r] + (size_t)(mc + 1) * 32 + mloc];
            }
        }
        // stage tile mc+2
        if (mc < 14) STAGE_SC((char*)lds + ((mc + 2) % 3) * 16384, mc + 2)
        const char* L = (const char*)lds + (mc % 3) * 16384;
#pragma unroll
        for (int es = 0; es < 4; es++) {
            int ph = (4 * es + kg) ^ sw;
            s16x8 bh = *(const s16x8*)(L + rbase + ph * 16);
            s16x8 bl = *(const s16x8*)(L + 8192 + rbase + ph * 16);
            acc[mc] = MFMA16(ah[es], bh, acc[mc]);
            acc[mc] = MFMA16(al[es], bh, acc[mc]);
            acc[mc] = MFMA16(ah[es], bl, acc[mc]);
        }
        // bias + tanh + mask with this tile's prefetched cd/ninf
#pragma unroll
        for (int r = 0; r < 4; r++) {
            acc[mc][r] = 10.f * fast_tanh(fmaf(acc[mc][r], invs, -a2ls * cdv[r]))
                       + nfv[r];
        }
        if (mc < 15) {
#pragma unroll
            for (int r = 0; r < 4; r++) { cdv[r] = ncd[r]; nfv[r] = nnf[r]; }
        }
    }
    // softmax over m (cross-wave via mh halves)
    float mx[4], sm[4];
#pragma unroll
    for (int r = 0; r < 4; r++) {
        float m = acc[0][r];
#pragma unroll
        for (int a = 1; a < 16; a++) m = fmaxf(m, acc[a][r]);
#pragma unroll
        for (int s = 1; s < 16; s <<= 1) m = fmaxf(m, __shfl_xor(m, s, 64));
        mx[r] = m;
    }
    int rl = ng * 16 + kg * 4;
    if (row == 0) {
#pragma unroll
        for (int r = 0; r < 4; r++) redm[rl + r][mh] = mx[r];
    }
    __syncthreads();
#pragma unroll
    for (int r = 0; r < 4; r++) {
        float m = fmaxf(redm[rl + r][0], redm[rl + r][1]);
        float s = 0.f;
#pragma unroll
        for (int a = 0; a < 16; a++) {
            float e = __expf(acc[a][r] - m);
            acc[a][r] = e;
            s += e;
        }
#pragma unroll
        for (int sh = 1; sh < 16; sh <<= 1) s += __shfl_xor(s, sh, 64);
        sm[r] = s;
    }
    if (row == 0) {
#pragma unroll
        for (int r = 0; r < 4; r++) reds[rl + r][mh] = sm[r];
    }
    __syncthreads();
#pragma unroll
    for (int r = 0; r < 4; r++) {
        float inv = 1.f / (reds[rl + r][0] + reds[rl + r][1]);
        size_t ro = ((size_t)b * N + n0 + rl + r) * M;
#pragma unroll
        for (int a = 0; a < 16; a++) {
            out[ro + a * 32 + mh * 16 + row] = acc[a][r] * inv;
        }
    }
}

extern "C" void kernel_launch(void* const* d_in, const int* in_sizes, int n_in,
                              void* d_out, int out_size, void* d_ws, size_t ws_size,
                              hipStream_t stream) {
    const float* encl  = (const float*)d_in[0];
    const float* loadv = (const float*)d_in[1];
    const float* cdist = (const float*)d_in[2];
    const float* ls    = (const float*)d_in[3];
    const float* ninf  = (const float*)d_in[4];
    const float* enc   = (const float*)d_in[5];
    const float* Wq    = (const float*)d_in[6];
    const float* Wk    = (const float*)d_in[7];
    const float* Wv    = (const float*)d_in[8];
    const float* a1    = (const float*)d_in[9];
    const float* a2    = (const float*)d_in[10];
    char* ws = (char*)d_ws;
    unsigned short* EKb     = (unsigned short*)(ws);                 // 33.5 MB
    unsigned short* EKVb    = (unsigned short*)(ws + 33554432);      // 33.5 MB
    float*          SQ      = (float*)(ws + 67108864);               // 33.5 MB
    unsigned short* Wk_hi   = (unsigned short*)(ws + 100663296);
    unsigned short* Wk_lo   = (unsigned short*)(ws + 100663296 + 32768);
    unsigned short* Wv_hi   = (unsigned short*)(ws + 100663296 + 65536);
    unsigned short* Wv_lo   = (unsigned short*)(ws + 100663296 + 98304);
    unsigned short* Wq_hi   = (unsigned short*)(ws + 100663296 + 131072);
    unsigned short* Wq_lo   = (unsigned short*)(ws + 100663296 + 163840);
    unsigned short* ENC_hi  = EKb;    // reuse dead EK/EKV regions after k_numden
    unsigned short* ENC_lo  = EKVb;
    float* out = (float*)d_out;

    k_prep_w<<<192, 256, 0, stream>>>(Wk, Wv, Wq, Wk_hi, Wk_lo, Wv_hi, Wv_lo, Wq_hi, Wq_lo);
    k_kv<<<dim3(8, 128), 256, 0, stream>>>(enc, Wk_hi, Wk_lo, Wv_hi, Wv_lo, EKb, EKVb);
    k_q<<<dim3(8, 128), 256, 0, stream>>>(encl, loadv, Wq, Wq_hi, Wq_lo, SQ);
    k_numden<<<1024, 256, 0, stream>>>(cdist, ninf, EKVb, EKb, SQ, a1, ls);
    k_encsplit<<<4096, 256, 0, stream>>>(enc, ENC_hi, ENC_lo);
    k_score<<<2048, 256, 0, stream>>>(SQ, ENC_hi, ENC_lo, cdist, ninf, a2, ls, out);
}